// Round 1
// baseline (93.470 us; speedup 1.0000x reference)
//
#include <hip/hip_runtime.h>
#include <hip/hip_fp16.h>

// Problem constants (reference: D=128 vars, H=16 hidden, B=8192 batch)
#define DD 128
#define HH 16
#define BB 8192

typedef _Float16 hf8 __attribute__((ext_vector_type(8)));
typedef _Float16 hf4 __attribute__((ext_vector_type(4)));
typedef _Float16 hf2 __attribute__((ext_vector_type(2)));
typedef float f32x4 __attribute__((ext_vector_type(4)));
typedef float f32x2 __attribute__((ext_vector_type(2)));

// packed f32->f16 (RTZ), bit-cast from the builtin's __fp16-based vector type
static __device__ __forceinline__ hf2 pkrtz(float a, float b) {
    return __builtin_bit_cast(hf2, __builtin_amdgcn_cvt_pkrtz(a, b));
}

// ---------------------------------------------------------------------------
// Fully fused kernel — ZERO workspace use (the 256 MiB d_ws poison fills were
// ~82 of the 91 us). Each block recomputes its 16-variable slice of
//   Wt[i][h][v] = f16( A[v,i] * W1[i,v,h] ),  A = sigmoid((2L+g1-g0)/T), diag 0
// into a 64 KB LDS tile in MFMA fragment layout, rows XOR-swizzled by
// ((h&7)<<4) so the main loop's ds_read_b128 (row stride 256 B) is
// bank-conflict-free. Main loop identical to the previous k_main but reads
// fragments from LDS. blockIdx.x==0 blocks also emit the A output.
// ---------------------------------------------------------------------------
__launch_bounds__(128)
__global__ void k_fused(const float* __restrict__ X, const float* __restrict__ L,
                        const float* __restrict__ Tptr, const float* __restrict__ g,
                        const float* __restrict__ W1, const float* __restrict__ b1,
                        const float* __restrict__ W2, const float* __restrict__ b2,
                        float* __restrict__ out, float* __restrict__ Aout) {
    extern __shared__ _Float16 wt[];   // [16 i][16 h][128 v] f16 = 64 KB, swizzled rows

    const int tid  = threadIdx.x;
    const int wave = tid >> 6;
    const int lane = tid & 63;
    const int m    = lane & 15;        // frag row/col index
    const int q    = lane >> 4;        // quad

    const int b0 = blockIdx.x * 128 + wave * 64;  // 64 batch rows per wave
    const int i0 = blockIdx.y * 16;               // variable group base

    // X fragments (B-operand): n=lane&15=b, k=q*8+j=v. Issued FIRST so the
    // HBM latency hides under the prep phase below.
    hf8 xb[4][4];
#pragma unroll
    for (int t = 0; t < 4; t++) {
        const float* xp = X + (size_t)(b0 + t * 16 + m) * DD + q * 8;
#pragma unroll
        for (int s = 0; s < 4; s++) {
            f32x4 lo = *(const f32x4*)(xp + s * 32);
            f32x4 hi = *(const f32x4*)(xp + s * 32 + 4);
            hf2 p0 = pkrtz(lo[0], lo[1]);
            hf2 p1 = pkrtz(lo[2], lo[3]);
            hf2 p2 = pkrtz(hi[0], hi[1]);
            hf2 p3 = pkrtz(hi[2], hi[3]);
            hf4 l4 = __builtin_shufflevector(p0, p1, 0, 1, 2, 3);
            hf4 h4 = __builtin_shufflevector(p2, p3, 0, 1, 2, 3);
            xb[t][s] = __builtin_shufflevector(l4, h4, 0, 1, 2, 3, 4, 5, 6, 7);
        }
    }

    // ---- prep: A (sigmoid) + Wt = A*W1 into LDS; each wave owns 8 i's ----
    // Lane handles v = 2*lane, 2*lane+1 -> one hf2 (v-pair) per h -> ds_write_b32.
    // Wt conversion is RTN scalar cast (identical numerics to old k_prep).
    const float tinv = 1.0f / Tptr[0];
    const int v0 = lane * 2;
#pragma unroll 2
    for (int kk = 0; kk < 8; kk++) {
        const int il = wave * 8 + kk;
        const int i  = i0 + il;
        const int vi0 = v0 * DD + i;
        const int vi1 = vi0 + DD;
        f32x2 g0 = *(const f32x2*)(g + 2 * (size_t)vi0);
        f32x2 g1 = *(const f32x2*)(g + 2 * (size_t)vi1);
        float z0 = (2.0f * L[vi0] + g0[1] - g0[0]) * tinv;
        float z1 = (2.0f * L[vi1] + g1[1] - g1[0]) * tinv;
        float a0 = 1.0f / (1.0f + __expf(-z0));
        float a1 = 1.0f / (1.0f + __expf(-z1));
        if (v0 == i)     a0 = 0.0f;
        if (v0 + 1 == i) a1 = 0.0f;
        if (blockIdx.x == 0) { Aout[vi0] = a0; Aout[vi1] = a1; }
        const float* w1p = W1 + ((size_t)i * DD + v0) * HH;   // h contiguous
        f32x4 wva[4], wvb[4];
#pragma unroll
        for (int s = 0; s < 4; s++) wva[s] = *(const f32x4*)(w1p + 4 * s);
#pragma unroll
        for (int s = 0; s < 4; s++) wvb[s] = *(const f32x4*)(w1p + HH + 4 * s);
        char* rowp = (char*)wt + il * (HH * 256);
        const int cb = 4 * lane;                              // byte offset of v-pair
#pragma unroll
        for (int h = 0; h < HH; h++) {
            hf2 val;
            val[0] = (_Float16)(a0 * wva[h >> 2][h & 3]);
            val[1] = (_Float16)(a1 * wvb[h >> 2][h & 3]);
            *(hf2*)(rowp + h * 256 + (cb ^ ((h & 7) << 4))) = val;
        }
    }

    // W2 column fragment + output acc init (b2 folded) — independent of LDS.
    f32x4 w2f = *(const f32x4*)(W2 + (i0 + m) * HH + q * 4);
    hf2 wlo = pkrtz(w2f[0], w2f[1]);
    hf2 whi = pkrtz(w2f[2], w2f[3]);
    hf4 w2self = __builtin_shufflevector(wlo, whi, 0, 1, 2, 3);
    const hf4 hzero = {(_Float16)0.f, (_Float16)0.f, (_Float16)0.f, (_Float16)0.f};
    const float b2v = b2[i0 + m];
    f32x4 acc2[4];
#pragma unroll
    for (int t = 0; t < 4; t++) acc2[t] = (f32x4){b2v, b2v, b2v, b2v};

    __syncthreads();

    // ---- main loop: hidden^T = Wt_i @ X^T, relu-pack, masked reduce MFMA ----
    const char* wbase = (const char*)wt + m * 256;
    const int swz = (m & 7) << 4;
#pragma unroll 2
    for (int ii = 0; ii < 16; ii++) {
        const int i = i0 + ii;
        const char* rp = wbase + ii * (HH * 256);
        f32x4 b1v = *(const f32x4*)(b1 + i * HH + q * 4);   // bias folded into acc
        f32x4 a[4] = {b1v, b1v, b1v, b1v};
#pragma unroll
        for (int s = 0; s < 4; s++) {
            hf8 wa = *(const hf8*)(rp + ((s * 64 + q * 16) ^ swz));  // ds_read_b128
#pragma unroll
            for (int t = 0; t < 4; t++)
                a[t] = __builtin_amdgcn_mfma_f32_16x16x32_f16(wa, xb[t][s], a[t], 0, 0, 0);
        }
        // relu + packed f16 cvt; lane's 4 values are h = q*4 + r.
        hf4 bfrag = (m == ii) ? w2self : hzero;
#pragma unroll
        for (int t = 0; t < 4; t++) {
            hf2 plo = pkrtz(__builtin_fmaxf(a[t][0], 0.f),
                            __builtin_fmaxf(a[t][1], 0.f));
            hf2 phi = pkrtz(__builtin_fmaxf(a[t][2], 0.f),
                            __builtin_fmaxf(a[t][3], 0.f));
            hf4 p = __builtin_shufflevector(plo, phi, 0, 1, 2, 3);
            acc2[t] = __builtin_amdgcn_mfma_f32_16x16x16f16(p, bfrag, acc2[t], 0, 0, 0);
        }
    }

    // Store: lane holds out[b = b0 + t*16 + q*4 + r][i0 + m].
#pragma unroll
    for (int t = 0; t < 4; t++)
#pragma unroll
        for (int r = 0; r < 4; r++)
            out[(size_t)(b0 + t * 16 + q * 4 + r) * DD + i0 + m] = acc2[t][r];
}

// ---------------------------------------------------------------------------
extern "C" void kernel_launch(void* const* d_in, const int* in_sizes, int n_in,
                              void* d_out, int out_size, void* d_ws, size_t ws_size,
                              hipStream_t stream) {
    const float* X  = (const float*)d_in[0];
    const float* L  = (const float*)d_in[1];
    const float* T  = (const float*)d_in[2];
    const float* g  = (const float*)d_in[3];
    const float* W1 = (const float*)d_in[4];
    const float* b1 = (const float*)d_in[5];
    const float* W2 = (const float*)d_in[6];
    const float* b2 = (const float*)d_in[7];

    float* recon = (float*)d_out;              // output 0: [BB, DD]
    float* Aout  = recon + (size_t)BB * DD;    // output 1: [DD, DD]

    (void)d_ws; (void)ws_size;                 // workspace deliberately UNUSED

    dim3 grid(BB / 128, DD / 16);              // 512 blocks x 2 waves
    k_fused<<<grid, 128, 65536, stream>>>(X, L, T, g, W1, b1, W2, b2, recon, Aout);
}

// Round 2
// 85.598 us; speedup vs baseline: 1.0920x; 1.0920x over previous
//
#include <hip/hip_runtime.h>
#include <hip/hip_fp16.h>

// Problem constants (reference: D=128 vars, H=16 hidden, B=8192 batch)
#define DD 128
#define HH 16
#define BB 8192

typedef _Float16 hf8 __attribute__((ext_vector_type(8)));
typedef _Float16 hf4 __attribute__((ext_vector_type(4)));
typedef _Float16 hf2 __attribute__((ext_vector_type(2)));
typedef float f32x4 __attribute__((ext_vector_type(4)));
typedef float f32x2 __attribute__((ext_vector_type(2)));

// packed f32->f16 (RTZ), bit-cast from the builtin's __fp16-based vector type
static __device__ __forceinline__ hf2 pkrtz(float a, float b) {
    return __builtin_bit_cast(hf2, __builtin_amdgcn_cvt_pkrtz(a, b));
}

// ---------------------------------------------------------------------------
// Prep v2: thread-per-(i,v).
//   A[v,i] = sigmoid((2*L[v,i] + g1 - g0)/T), diag zeroed   (fp32 exact)
//   Wt[i][h][v] = f16( A[v,i] * W1[i,v,h] )                 (MFMA frag layout)
// One coalesced 64B W1 read + ONE expf per thread (R0 did 16x redundant expf
// and stride-64B uncoalesced W1 reads). Writes per h are 128B-contiguous.
// ---------------------------------------------------------------------------
__global__ void k_prep(const float* __restrict__ L, const float* __restrict__ Tptr,
                       const float* __restrict__ g, const float* __restrict__ W1,
                       float* __restrict__ Aout, _Float16* __restrict__ Wt) {
    int gid = blockIdx.x * 64 + threadIdx.x;   // i*DD + v
    int v = gid & (DD - 1);
    int i = gid >> 7;
    int vi = v * DD + i;
    float t = Tptr[0];
    f32x2 gg = *(const f32x2*)(g + 2 * (size_t)vi);
    float z = (2.0f * L[vi] + gg[1] - gg[0]) / t;
    float a = 1.0f / (1.0f + __expf(-z));
    if (v == i) a = 0.0f;
    Aout[vi] = a;
    const float* w1p = W1 + ((size_t)i * DD + v) * HH;   // h contiguous, 64B
    f32x4 w[4];
#pragma unroll
    for (int s = 0; s < 4; s++) w[s] = *(const f32x4*)(w1p + 4 * s);
#pragma unroll
    for (int h = 0; h < HH; h++)
        Wt[i * (HH * DD) + h * DD + v] = (_Float16)(a * w[h >> 2][h & 3]);
}

// ---------------------------------------------------------------------------
// Main kernel, R0 structure (global Wt reads; it is L2-resident, 512 KB) with
// latency fixes for the 1-wave/SIMD regime:
//  * full unroll of the 16-var loop with an explicit 2-deep register
//    double-buffer (wa0/wa1, statically indexed) prefetching ii+1's Wt
//    fragments before ii's MFMAs — hides the ~200cy L2 latency that was
//    exposed each iteration.
//  * all 16 b1 vectors hoisted into registers before the loop.
//  * __launch_bounds__(128,2) caps VGPR at 256 — occupancy is grid-limited
//    at 1 wave/SIMD anyway, so registers are free.
// ---------------------------------------------------------------------------
__launch_bounds__(128, 2)
__global__ void k_main(const float* __restrict__ X, const _Float16* __restrict__ Wt,
                       const float* __restrict__ b1, const float* __restrict__ W2,
                       const float* __restrict__ b2, float* __restrict__ out) {
    const int tid  = threadIdx.x;
    const int wave = tid >> 6;
    const int lane = tid & 63;
    const int m    = lane & 15;        // frag row/col index
    const int q    = lane >> 4;        // quad

    const int b0 = blockIdx.x * 128 + wave * 64;  // 64 batch rows per wave
    const int i0 = blockIdx.y * 16;               // variable group base

    // X fragments (B-operand): n=lane&15=b, k=q*8+j=v. fp32 -> f16 packed cvt.
    hf8 xb[4][4];
#pragma unroll
    for (int t = 0; t < 4; t++) {
        const float* xp = X + (size_t)(b0 + t * 16 + m) * DD + q * 8;
#pragma unroll
        for (int s = 0; s < 4; s++) {
            f32x4 lo = *(const f32x4*)(xp + s * 32);
            f32x4 hi = *(const f32x4*)(xp + s * 32 + 4);
            hf2 p0 = pkrtz(lo[0], lo[1]);
            hf2 p1 = pkrtz(lo[2], lo[3]);
            hf2 p2 = pkrtz(hi[0], hi[1]);
            hf2 p3 = pkrtz(hi[2], hi[3]);
            hf4 l4 = __builtin_shufflevector(p0, p1, 0, 1, 2, 3);
            hf4 h4 = __builtin_shufflevector(p2, p3, 0, 1, 2, 3);
            xb[t][s] = __builtin_shufflevector(l4, h4, 0, 1, 2, 3, 4, 5, 6, 7);
        }
    }

    // W2 column fragment: lane holds W2[i0+m][q*4+j] as f16 (reduction B-op).
    f32x4 w2f = *(const f32x4*)(W2 + (i0 + m) * HH + q * 4);
    hf2 wlo = pkrtz(w2f[0], w2f[1]);
    hf2 whi = pkrtz(w2f[2], w2f[3]);
    hf4 w2self = __builtin_shufflevector(wlo, whi, 0, 1, 2, 3);
    const hf4 hzero = {(_Float16)0.f, (_Float16)0.f, (_Float16)0.f, (_Float16)0.f};

    // Output accumulators, b2 folded into init (col = lane&15 = ii -> b2[i0+m]).
    const float b2v = b2[i0 + m];
    f32x4 acc2[4];
#pragma unroll
    for (int t = 0; t < 4; t++) acc2[t] = (f32x4){b2v, b2v, b2v, b2v};

    // Hoist all 16 b1 acc-init vectors (64 VGPR, free at this occupancy).
    f32x4 b1all[16];
#pragma unroll
    for (int ii = 0; ii < 16; ii++)
        b1all[ii] = *(const f32x4*)(b1 + (i0 + ii) * HH + q * 4);

    // Wt fragment base for this lane: row h=m of var i, k-offset q*8.
    const _Float16* wbase = Wt + ((size_t)i0 * HH + m) * DD + q * 8;

    // 2-deep register double-buffer over ii (statically indexed).
    hf8 wa0[4], wa1[4];
#pragma unroll
    for (int s = 0; s < 4; s++) wa0[s] = *(const hf8*)(wbase + s * 32);

#define STEP(IIC, WUSE, WPRE, PRE_II)                                          \
    {                                                                          \
        if ((PRE_II) < 16) {                                                   \
            const _Float16* np = wbase + (size_t)(PRE_II) * (HH * DD);         \
            _Pragma("unroll")                                                  \
            for (int s = 0; s < 4; s++) WPRE[s] = *(const hf8*)(np + s * 32);  \
        }                                                                      \
        f32x4 b1v = b1all[(IIC)];                                              \
        f32x4 a[4] = {b1v, b1v, b1v, b1v};                                     \
        _Pragma("unroll")                                                      \
        for (int s = 0; s < 4; s++) {                                          \
            _Pragma("unroll")                                                  \
            for (int t = 0; t < 4; t++)                                        \
                a[t] = __builtin_amdgcn_mfma_f32_16x16x32_f16(WUSE[s], xb[t][s], a[t], 0, 0, 0); \
        }                                                                      \
        hf4 bfrag = (m == (IIC)) ? w2self : hzero;                             \
        _Pragma("unroll")                                                      \
        for (int t = 0; t < 4; t++) {                                          \
            hf2 plo = pkrtz(__builtin_fmaxf(a[t][0], 0.f),                     \
                            __builtin_fmaxf(a[t][1], 0.f));                    \
            hf2 phi = pkrtz(__builtin_fmaxf(a[t][2], 0.f),                     \
                            __builtin_fmaxf(a[t][3], 0.f));                    \
            hf4 p = __builtin_shufflevector(plo, phi, 0, 1, 2, 3);             \
            acc2[t] = __builtin_amdgcn_mfma_f32_16x16x16f16(p, bfrag, acc2[t], 0, 0, 0); \
        }                                                                      \
    }

#pragma unroll
    for (int jj = 0; jj < 8; jj++) {
        STEP(2 * jj,     wa0, wa1, 2 * jj + 1);
        STEP(2 * jj + 1, wa1, wa0, 2 * jj + 2);
    }
#undef STEP

    // Store: lane holds out[b = b0 + t*16 + q*4 + r][i0 + m].
#pragma unroll
    for (int t = 0; t < 4; t++)
#pragma unroll
        for (int r = 0; r < 4; r++)
            out[(size_t)(b0 + t * 16 + q * 4 + r) * DD + i0 + m] = acc2[t][r];
}

// ---------------------------------------------------------------------------
extern "C" void kernel_launch(void* const* d_in, const int* in_sizes, int n_in,
                              void* d_out, int out_size, void* d_ws, size_t ws_size,
                              hipStream_t stream) {
    const float* X  = (const float*)d_in[0];
    const float* L  = (const float*)d_in[1];
    const float* T  = (const float*)d_in[2];
    const float* g  = (const float*)d_in[3];
    const float* W1 = (const float*)d_in[4];
    const float* b1 = (const float*)d_in[5];
    const float* W2 = (const float*)d_in[6];
    const float* b2 = (const float*)d_in[7];

    float* recon = (float*)d_out;              // output 0: [BB, DD]
    float* Aout  = recon + (size_t)BB * DD;    // output 1: [DD, DD]

    _Float16* Wt = (_Float16*)d_ws;            // [DD][HH][DD] f16, 512 KB

    k_prep<<<(DD * DD) / 64, 64, 0, stream>>>(L, T, g, W1, Aout, Wt);

    dim3 grid(BB / 128, DD / 16);              // 512 blocks x 2 waves
    k_main<<<grid, 128, 0, stream>>>(X, Wt, b1, W2, b2, recon);
}